// Round 7
// baseline (372.110 us; speedup 1.0000x reference)
//
#include <hip/hip_runtime.h>
#include <math.h>

#define HWP 4096
#define CCH 256
#define NN  1024
#define DD  256
#define ZQ_SIZE (8 * DD * HWP)       // 8388608 floats = 33554432 B
#define MARGIN 1e-4f
#define WLCAP 4096

typedef _Float16 h8 __attribute__((ext_vector_type(8)));
typedef float    f4 __attribute__((ext_vector_type(4)));

__device__ __forceinline__ void gl_lds16(const _Float16* g, void* lds) {
    __builtin_amdgcn_global_load_lds(
        (const __attribute__((address_space(1))) unsigned int*)(g),
        (__attribute__((address_space(3))) unsigned int*)(lds),
        16, 0, 0);
}

// ---------- K1: split w -> wh/wl fp16 [1024][256]; zero worklist counter ----
__global__ __launch_bounds__(256) void split_w_k(
    const float* __restrict__ w, _Float16* __restrict__ wh, _Float16* __restrict__ wl,
    int* __restrict__ wcount)
{
    if (blockIdx.x == 0 && threadIdx.x == 0) *wcount = 0;
    const int i = blockIdx.x * 256 + threadIdx.x;
    const float x = w[i];
    const _Float16 h = (_Float16)x;
    wh[i] = h;
    wl[i] = (_Float16)(x - (float)h);
}

// ---------- K2: z -> zTh/zTl [pix][c] fp16 (transpose + split; R3-validated) -
__global__ __launch_bounds__(256) void split_zt_k(
    const float* __restrict__ z, _Float16* __restrict__ zTh, _Float16* __restrict__ zTl)
{
    __shared__ float t[64][68];
    const int tid = threadIdx.x;
    const int pt  = blockIdx.x >> 2;
    const int ct  = blockIdx.x & 3;
    const int b   = pt >> 6;
    const int p0  = (pt & 63) << 6;
    const int c0  = ct << 6;
    const float* zb = z + ((size_t)b * CCH + c0) * HWP + p0;
    {
        const int px4 = tid & 15, cr = tid >> 4;
#pragma unroll
        for (int it = 0; it < 4; ++it) {
            const int c = it * 16 + cr;
            const float4 v = *(const float4*)(zb + (size_t)c * HWP + px4 * 4);
            *(float4*)&t[c][px4 * 4] = v;
        }
    }
    __syncthreads();
    {
        const int c8 = tid & 7, pxl = tid >> 3;
#pragma unroll
        for (int it = 0; it < 2; ++it) {
            const int px = it * 32 + pxl;
            _Float16 hv[8], lv[8];
#pragma unroll
            for (int i = 0; i < 8; ++i) {
                const float x = t[c8 * 8 + i][px];
                const _Float16 h = (_Float16)x;
                hv[i] = h;
                lv[i] = (_Float16)(x - (float)h);
            }
            const size_t off = (size_t)(pt * 64 + px) * CCH + c0 + c8 * 8;
            *(h8*)(zTh + off) = *(const h8*)hv;
            *(h8*)(zTl + off) = *(const h8*)lv;
        }
    }
}

// ---------- K3: full-row MFMA logits, 3 products, final top2 + worklist -----
// 512 blocks x 256 thr (4 waves). Block: 64 px x 1024 codes (nt-loop of 8
// tiles of 128 n). Wave wv owns n-slice wv*32 within each tile: 4x2 frags.
// Per kc-chunk (BK=32): stage zh/zl (64x32) + wh/wl (128x32) = 24 KB via
// global_load_lds(16B). 24 MFMA per wave per chunk.
__global__ __launch_bounds__(256) void mfma_full_k(
    const _Float16* __restrict__ zTh, const _Float16* __restrict__ zTl,
    const _Float16* __restrict__ wh,  const _Float16* __restrict__ wl,
    const float* __restrict__ bias,
    unsigned short* __restrict__ idx16, int* __restrict__ wcount,
    int* __restrict__ wlist, float* __restrict__ out)
{
    __shared__ __align__(16) char smem[27648]; // zh 4K | zl 4K | wh 8K | wl 8K | merge 3K
    float* s_best = (float*)(smem + 24576);    // [4][64]
    float* s_sec  = (float*)(smem + 24576 + 1024);
    int*   s_idx  = (int*)  (smem + 24576 + 2048);

    const int tid = threadIdx.x;
    const int l   = tid & 63;
    const int wv  = tid >> 6;
    const int c15 = l & 15, g = l >> 4;
    const int pix0 = blockIdx.x * 64;
    const int srow = l >> 2, scol = l & 3;

    float best[16], sec[16]; int bidx[16];
#pragma unroll
    for (int s = 0; s < 16; ++s) { best[s] = -INFINITY; sec[s] = -INFINITY; bidx[s] = 0; }

#pragma unroll 1
    for (int nt = 0; nt < 8; ++nt) {
        const int n0 = nt * 128;
        f4 acc[4][2];
#pragma unroll
        for (int mf = 0; mf < 4; ++mf)
#pragma unroll
            for (int nf = 0; nf < 2; ++nf) acc[mf][nf] = (f4)0.f;

#pragma unroll 1
        for (int kc = 0; kc < 8; ++kc) {
            __syncthreads();                     // prev chunk's readers done
            const int koff = kc * 32 + scol * 8;
#pragma unroll
            for (int t = 0; t < 6; ++t) {
                const int idx = wv * 6 + t;      // 0..23: zh 0-3 | zl 4-7 | wh 8-15 | wl 16-23
                if (idx < 4) {
                    gl_lds16(zTh + (size_t)(pix0 + idx * 16 + srow) * CCH + koff,
                             smem + idx * 1024 + 0);
                } else if (idx < 8) {
                    gl_lds16(zTl + (size_t)(pix0 + (idx - 4) * 16 + srow) * CCH + koff,
                             smem + 4096 + (idx - 4) * 1024);
                } else if (idx < 16) {
                    gl_lds16(wh + (size_t)(n0 + (idx - 8) * 16 + srow) * CCH + koff,
                             smem + 8192 + (idx - 8) * 1024);
                } else {
                    gl_lds16(wl + (size_t)(n0 + (idx - 16) * 16 + srow) * CCH + koff,
                             smem + 16384 + (idx - 16) * 1024);
                }
            }
            __syncthreads();                     // vmcnt drain + barrier
            h8 ah[4], al[4];
#pragma unroll
            for (int mf = 0; mf < 4; ++mf) {
                const int ao = (mf * 16 + c15) * 64 + g * 16;
                ah[mf] = *(const h8*)(smem + ao);
                al[mf] = *(const h8*)(smem + 4096 + ao);
            }
#pragma unroll
            for (int nf = 0; nf < 2; ++nf) {
                const int bo = (wv * 32 + nf * 16 + c15) * 64 + g * 16;
                const h8 bh = *(const h8*)(smem + 8192 + bo);
                const h8 bl = *(const h8*)(smem + 16384 + bo);
#pragma unroll
                for (int mf = 0; mf < 4; ++mf) {
                    acc[mf][nf] = __builtin_amdgcn_mfma_f32_16x16x32_f16(ah[mf], bh, acc[mf][nf], 0, 0, 0);
                    acc[mf][nf] = __builtin_amdgcn_mfma_f32_16x16x32_f16(ah[mf], bl, acc[mf][nf], 0, 0, 0);
                    acc[mf][nf] = __builtin_amdgcn_mfma_f32_16x16x32_f16(al[mf], bh, acc[mf][nf], 0, 0, 0);
                }
            }
        }
        // fold (+bias) into per-lane top2
#pragma unroll
        for (int nf = 0; nf < 2; ++nf) {
            const int n_abs = n0 + wv * 32 + nf * 16 + c15;
            const float bv = bias[n_abs];
#pragma unroll
            for (int mf = 0; mf < 4; ++mf)
#pragma unroll
                for (int r = 0; r < 4; ++r) {
                    const float v = acc[mf][nf][r] + bv;
                    const int s = mf * 4 + r;
                    if (v > best[s]) { sec[s] = best[s]; best[s] = v; bidx[s] = n_abs; }
                    else if (v > sec[s]) sec[s] = v;
                }
        }
    }

    // butterfly over the 16 col-lanes (R5-validated)
#pragma unroll
    for (int d = 1; d < 16; d <<= 1) {
#pragma unroll
        for (int s = 0; s < 16; ++s) {
            const float ob = __shfl_xor(best[s], d, 64);
            const float os = __shfl_xor(sec[s], d, 64);
            const int   oi = __shfl_xor(bidx[s], d, 64);
            if (ob > best[s])       { sec[s] = fmaxf(best[s], os); best[s] = ob; bidx[s] = oi; }
            else if (ob == best[s]) { sec[s] = ob; bidx[s] = (oi < bidx[s]) ? oi : bidx[s]; }
            else                    { sec[s] = fmaxf(sec[s], ob); }
        }
    }
    // publish: one candidate per (wave, pixel)
#pragma unroll
    for (int s = 0; s < 16; ++s) {
        if (c15 == s) {
            const int pxl = (s >> 2) * 16 + g * 4 + (s & 3);   // 0..63
            s_best[wv * 64 + pxl] = best[s];
            s_sec [wv * 64 + pxl] = sec[s];
            s_idx [wv * 64 + pxl] = bidx[s];
        }
    }
    __syncthreads();
    if (tid < 64) {
        float b0 = s_best[tid], s0 = s_sec[tid]; int i0 = s_idx[tid];
#pragma unroll
        for (int c = 1; c < 4; ++c) {
            const float ob = s_best[c * 64 + tid], os = s_sec[c * 64 + tid];
            const int   oi = s_idx[c * 64 + tid];
            // wave n-ranges interleave: explicit min-idx tie-break
            if (ob > b0 || (ob == b0 && oi < i0)) { s0 = fmaxf(b0, os); b0 = ob; i0 = oi; }
            else                                  { s0 = fmaxf(s0, ob); }
        }
        const int pix = pix0 + tid;
        idx16[pix] = (unsigned short)i0;
        out[ZQ_SIZE + 1 + pix] = (float)i0;
        if (b0 - s0 < MARGIN) {
            const int pos = atomicAdd(wcount, 1);
            if (pos < WLCAP) wlist[pos] = pix;
        }
    }
    if (blockIdx.x == 0 && tid == 0) out[ZQ_SIZE] = 0.0f;
}

// ---------- K4: exact-fp32 fixup, wave-per-row coalesced, worklist-driven ---
__global__ __launch_bounds__(256) void fixup_k(
    const float* __restrict__ z, const float* __restrict__ w,
    const float* __restrict__ bias,
    const int* __restrict__ wcount, const int* __restrict__ wlist,
    unsigned short* __restrict__ idx16, float* __restrict__ out)
{
    __shared__ float zsh[256];
    __shared__ float m_v[4];
    __shared__ int   m_i[4];

    const int tid = threadIdx.x;
    const int l = tid & 63, wv = tid >> 6;
    int nw = *wcount;
    if (nw > WLCAP) nw = WLCAP;

    for (int e = blockIdx.x; e < nw; e += 64) {
        const int pix = wlist[e];
        const int b = pix >> 12, p = pix & 4095;
        __syncthreads();                         // zsh reuse across entries
        zsh[tid] = z[((size_t)b * CCH + tid) * HWP + p];
        __syncthreads();
        const float4 z4 = *(const float4*)&zsh[l * 4];
        float bv = -INFINITY; int bi = 0;
        for (int r = 0; r < 256; ++r) {
            const int n = wv * 256 + r;
            const float4 wr = *(const float4*)(w + (size_t)n * CCH + l * 4);
            float part = wr.x * z4.x + wr.y * z4.y + wr.z * z4.z + wr.w * z4.w;
#pragma unroll
            for (int d = 1; d < 64; d <<= 1)
                part += __shfl_xor(part, d, 64);
            const float v = part + bias[n];
            if (v > bv) { bv = v; bi = n; }      // r ascending: lowest idx on tie
        }
        if (l == 0) { m_v[wv] = bv; m_i[wv] = bi; }
        __syncthreads();
        if (tid == 0) {
            float v = m_v[0]; int i = m_i[0];
#pragma unroll
            for (int t = 1; t < 4; ++t)
                if (m_v[t] > v || (m_v[t] == v && m_i[t] < i)) { v = m_v[t]; i = m_i[t]; }
            idx16[pix] = (unsigned short)i;
            out[ZQ_SIZE + 1 + pix] = (float)i;
        }
    }
}

// ---------- K5: gather epilogue (overwrites z_q; zTh/zTl dead) --------------
__global__ __launch_bounds__(256) void gather_k(
    const float* __restrict__ embed, const unsigned short* __restrict__ idx16,
    float* __restrict__ out)
{
    __shared__ __align__(16) float tile[64][257];
    __shared__ int indsh[64];

    const int tid = threadIdx.x;
    const int blk = blockIdx.x;
    const int b = blk >> 6, p0 = (blk & 63) << 6;
    const int pix0 = blk * 64;

    if (tid < 64) indsh[tid] = (int)idx16[pix0 + tid];
    __syncthreads();

    const int lq = tid & 63, wq = tid >> 6;
    for (int it = 0; it < 16; ++it) {
        const int p   = it * 4 + wq;
        const int row = indsh[p];
        const float4 e = *(const float4*)(embed + (size_t)row * DD + lq * 4);
        tile[p][lq * 4 + 0] = e.x;
        tile[p][lq * 4 + 1] = e.y;
        tile[p][lq * 4 + 2] = e.z;
        tile[p][lq * 4 + 3] = e.w;
    }
    __syncthreads();
    float* outz = out + (size_t)b * DD * HWP + p0;
    for (int dd = 0; dd < 64; ++dd) {
        const int d = dd * 4 + wq;
        outz[(size_t)d * HWP + lq] = tile[lq][d];
    }
}

extern "C" void kernel_launch(void* const* d_in, const int* in_sizes, int n_in,
                              void* d_out, int out_size, void* d_ws, size_t ws_size,
                              hipStream_t stream) {
    const float* z     = (const float*)d_in[0];
    const float* w     = (const float*)d_in[1];
    const float* bias  = (const float*)d_in[2];
    const float* embed = (const float*)d_in[3];
    float* out = (float*)d_out;

    // ws (1.14 MB — within proven budget):
    //   wh 512K | wl 512K | idx16 64K | wcount 256B | wlist 16K
    _Float16* wh = (_Float16*)d_ws;
    _Float16* wl = (_Float16*)((char*)d_ws + 524288);
    unsigned short* idx16 = (unsigned short*)((char*)d_ws + 1048576);
    int* wcount = (int*)((char*)d_ws + 1114112);
    int* wlist  = (int*)((char*)d_ws + 1114368);

    // d_out scratch (dead before gather_k overwrites with z_q):
    //   zTh [0,16MB) | zTl [16,32MB)
    _Float16* zTh = (_Float16*)d_out;
    _Float16* zTl = (_Float16*)((char*)d_out + 16777216);

    hipLaunchKernelGGL(split_w_k,   dim3(1024), dim3(256), 0, stream, w, wh, wl, wcount);
    hipLaunchKernelGGL(split_zt_k,  dim3(2048), dim3(256), 0, stream, z, zTh, zTl);
    hipLaunchKernelGGL(mfma_full_k, dim3(512),  dim3(256), 0, stream,
                       zTh, zTl, wh, wl, bias, idx16, wcount, wlist, out);
    hipLaunchKernelGGL(fixup_k,     dim3(64),   dim3(256), 0, stream,
                       z, w, bias, wcount, wlist, idx16, out);
    hipLaunchKernelGGL(gather_k,    dim3(512),  dim3(256), 0, stream,
                       embed, idx16, out);
}

// Round 8
// 263.557 us; speedup vs baseline: 1.4119x; 1.4119x over previous
//
#include <hip/hip_runtime.h>
#include <math.h>

#define HWP 4096
#define CCH 256
#define NN  1024
#define DD  256
#define ZQ_SIZE (8 * DD * HWP)       // 8388608 floats = 33554432 B
#define MARGIN 1e-4f
#define WLCAP 4096

typedef _Float16 h8 __attribute__((ext_vector_type(8)));
typedef float    f4 __attribute__((ext_vector_type(4)));

// ---------- K1: split w -> wh/wl fp16 [1024][256]; zero worklist counter ----
__global__ __launch_bounds__(256) void split_w_k(
    const float* __restrict__ w, _Float16* __restrict__ wh, _Float16* __restrict__ wl,
    int* __restrict__ wcount)
{
    if (blockIdx.x == 0 && threadIdx.x == 0) *wcount = 0;
    const int i = blockIdx.x * 256 + threadIdx.x;
    const float x = w[i];
    const _Float16 h = (_Float16)x;
    wh[i] = h;
    wl[i] = (_Float16)(x - (float)h);
}

// ---------- K2: z -> zTh/zTl [pix][c] fp16 (transpose + split; validated) ---
__global__ __launch_bounds__(256) void split_zt_k(
    const float* __restrict__ z, _Float16* __restrict__ zTh, _Float16* __restrict__ zTl)
{
    __shared__ float t[64][68];
    const int tid = threadIdx.x;
    const int pt  = blockIdx.x >> 2;
    const int ct  = blockIdx.x & 3;
    const int b   = pt >> 6;
    const int p0  = (pt & 63) << 6;
    const int c0  = ct << 6;
    const float* zb = z + ((size_t)b * CCH + c0) * HWP + p0;
    {
        const int px4 = tid & 15, cr = tid >> 4;
#pragma unroll
        for (int it = 0; it < 4; ++it) {
            const int c = it * 16 + cr;
            const float4 v = *(const float4*)(zb + (size_t)c * HWP + px4 * 4);
            *(float4*)&t[c][px4 * 4] = v;
        }
    }
    __syncthreads();
    {
        const int c8 = tid & 7, pxl = tid >> 3;
#pragma unroll
        for (int it = 0; it < 2; ++it) {
            const int px = it * 32 + pxl;
            _Float16 hv[8], lv[8];
#pragma unroll
            for (int i = 0; i < 8; ++i) {
                const float x = t[c8 * 8 + i][px];
                const _Float16 h = (_Float16)x;
                hv[i] = h;
                lv[i] = (_Float16)(x - (float)h);
            }
            const size_t off = (size_t)(pt * 64 + px) * CCH + c0 + c8 * 8;
            *(h8*)(zTh + off) = *(const h8*)hv;
            *(h8*)(zTl + off) = *(const h8*)lv;
        }
    }
}

// ---------- K3: barrier-free-K-loop MFMA logits + top2 + worklist ----------
// 1024 blocks x 256 thr (4 waves). Block: 32 px x all 1024 n.
// zh/zl staged in LDS ONCE (rows padded to 528 B -> uniform b128 banks);
// w-fragments streamed straight from global/L2 into registers (no barrier,
// no LDS round-trip). Wave wv owns n in [wv*256, wv*256+256): nt-loop of 8
// x 32 n (2 nf). 3 products zh*wh + zh*wl + zl*wh (R3/R7-validated numerics).
__global__ __launch_bounds__(256, 4) void mfma_full_k(
    const _Float16* __restrict__ zTh, const _Float16* __restrict__ zTl,
    const _Float16* __restrict__ wh,  const _Float16* __restrict__ wl,
    const float* __restrict__ bias,
    unsigned short* __restrict__ idx16, int* __restrict__ wcount,
    int* __restrict__ wlist, float* __restrict__ out)
{
    __shared__ __align__(16) char smem[35328]; // zh 16896 | zl 16896 | merge 1536
    float* s_best = (float*)(smem + 33792);    // [4][32]
    float* s_sec  = (float*)(smem + 34304);
    int*   s_idx  = (int*)  (smem + 34816);

    const int tid = threadIdx.x;
    const int l   = tid & 63;
    const int wv  = tid >> 6;
    const int c15 = l & 15, g = l >> 4;
    const int pix0 = blockIdx.x * 32;

    // Stage zh/zl once: thread t -> row r=t>>3 (0..31), segment seg=t&7 (64 B).
    {
        const int r = tid >> 3, seg = tid & 7;
        const int4* gph = (const int4*)(zTh + (size_t)(pix0 + r) * CCH + seg * 32);
        const int4* gpl = (const int4*)(zTl + (size_t)(pix0 + r) * CCH + seg * 32);
        int4* dph = (int4*)(smem + r * 528 + seg * 64);
        int4* dpl = (int4*)(smem + 16896 + r * 528 + seg * 64);
#pragma unroll
        for (int i = 0; i < 4; ++i) dph[i] = gph[i];
#pragma unroll
        for (int i = 0; i < 4; ++i) dpl[i] = gpl[i];
    }
    __syncthreads();   // the ONLY barrier before the merge

    float best[8], sec[8]; int bidx[8];
#pragma unroll
    for (int s = 0; s < 8; ++s) { best[s] = -INFINITY; sec[s] = -INFINITY; bidx[s] = 0; }

#pragma unroll 1
    for (int nt = 0; nt < 8; ++nt) {
        const int n0 = wv * 256 + nt * 32;
        f4 acc[2][2];
#pragma unroll
        for (int mf = 0; mf < 2; ++mf)
#pragma unroll
            for (int nf = 0; nf < 2; ++nf) acc[mf][nf] = (f4)0.f;

#pragma unroll 2
        for (int kc = 0; kc < 8; ++kc) {
            h8 ah[2], al[2];
#pragma unroll
            for (int mf = 0; mf < 2; ++mf) {
                const int ao = (mf * 16 + c15) * 528 + kc * 64 + g * 16;
                ah[mf] = *(const h8*)(smem + ao);
                al[mf] = *(const h8*)(smem + 16896 + ao);
            }
            h8 bh[2], bl[2];
#pragma unroll
            for (int nf = 0; nf < 2; ++nf) {
                const size_t bo = (size_t)(n0 + nf * 16 + c15) * CCH + kc * 32 + g * 8;
                bh[nf] = *(const h8*)(wh + bo);
                bl[nf] = *(const h8*)(wl + bo);
            }
#pragma unroll
            for (int mf = 0; mf < 2; ++mf)
#pragma unroll
                for (int nf = 0; nf < 2; ++nf) {
                    acc[mf][nf] = __builtin_amdgcn_mfma_f32_16x16x32_f16(ah[mf], bh[nf], acc[mf][nf], 0, 0, 0);
                    acc[mf][nf] = __builtin_amdgcn_mfma_f32_16x16x32_f16(ah[mf], bl[nf], acc[mf][nf], 0, 0, 0);
                    acc[mf][nf] = __builtin_amdgcn_mfma_f32_16x16x32_f16(al[mf], bh[nf], acc[mf][nf], 0, 0, 0);
                }
        }
        // fold (+bias) into per-lane top2 (n ascending per lane -> strict >)
#pragma unroll
        for (int nf = 0; nf < 2; ++nf) {
            const int n_abs = n0 + nf * 16 + c15;
            const float bv = bias[n_abs];
#pragma unroll
            for (int mf = 0; mf < 2; ++mf)
#pragma unroll
                for (int r = 0; r < 4; ++r) {
                    const float v = acc[mf][nf][r] + bv;
                    const int s = mf * 4 + r;
                    if (v > best[s]) { sec[s] = best[s]; best[s] = v; bidx[s] = n_abs; }
                    else if (v > sec[s]) sec[s] = v;
                }
        }
    }

    // butterfly over the 16 col-lanes (validated)
#pragma unroll
    for (int d = 1; d < 16; d <<= 1) {
#pragma unroll
        for (int s = 0; s < 8; ++s) {
            const float ob = __shfl_xor(best[s], d, 64);
            const float os = __shfl_xor(sec[s], d, 64);
            const int   oi = __shfl_xor(bidx[s], d, 64);
            if (ob > best[s])       { sec[s] = fmaxf(best[s], os); best[s] = ob; bidx[s] = oi; }
            else if (ob == best[s]) { sec[s] = ob; bidx[s] = (oi < bidx[s]) ? oi : bidx[s]; }
            else                    { sec[s] = fmaxf(sec[s], ob); }
        }
    }
    // publish: slot s -> pixel (s>>2)*16 + g*4 + (s&3)
#pragma unroll
    for (int s = 0; s < 8; ++s) {
        if (c15 == s) {
            const int px = (s >> 2) * 16 + g * 4 + (s & 3);   // 0..31
            s_best[wv * 32 + px] = best[s];
            s_sec [wv * 32 + px] = sec[s];
            s_idx [wv * 32 + px] = bidx[s];
        }
    }
    __syncthreads();
    if (tid < 32) {
        float b0 = s_best[tid], s0 = s_sec[tid]; int i0 = s_idx[tid];
#pragma unroll
        for (int c = 1; c < 4; ++c) {
            const float ob = s_best[c * 32 + tid], os = s_sec[c * 32 + tid];
            const int   oi = s_idx[c * 32 + tid];
            if (ob > b0 || (ob == b0 && oi < i0)) { s0 = fmaxf(b0, os); b0 = ob; i0 = oi; }
            else                                  { s0 = fmaxf(s0, ob); }
        }
        const int pix = pix0 + tid;
        idx16[pix] = (unsigned short)i0;
        out[ZQ_SIZE + 1 + pix] = (float)i0;
        if (b0 - s0 < MARGIN) {
            const int pos = atomicAdd(wcount, 1);
            if (pos < WLCAP) wlist[pos] = pix;
        }
    }
    if (blockIdx.x == 0 && tid == 0) out[ZQ_SIZE] = 0.0f;
}

// ---------- K4: exact-fp32 fixup — grouped rows, 2-shuffle reduce ----------
// 256 blocks; entry e -> block e (one pixel in flight per block, ~40 total).
// Wave wv owns rows [wv*256, wv*256+256) in 16 groups of 16: lane (c15,q)
// computes quarter-dot of row n0+c15 over c in [q*64, q*64+64); xor-16/32
// sums quarters; per-lane top1 then butterfly + cross-wave merge.
__global__ __launch_bounds__(256) void fixup_k(
    const float* __restrict__ z, const float* __restrict__ w,
    const float* __restrict__ bias,
    const int* __restrict__ wcount, const int* __restrict__ wlist,
    unsigned short* __restrict__ idx16, float* __restrict__ out)
{
    __shared__ float zsh[256];
    __shared__ float m_v[4];
    __shared__ int   m_i[4];

    const int tid = threadIdx.x;
    const int l = tid & 63, wv = tid >> 6;
    const int c15 = l & 15, q = l >> 4;
    int nw = *wcount;
    if (nw > WLCAP) nw = WLCAP;

    for (int e = blockIdx.x; e < nw; e += 256) {
        const int pix = wlist[e];
        const int b = pix >> 12, p = pix & 4095;
        __syncthreads();                         // zsh reuse across entries
        zsh[tid] = z[((size_t)b * CCH + tid) * HWP + p];
        __syncthreads();

        float best = -INFINITY; int bi = 0;
        for (int g16 = 0; g16 < 16; ++g16) {
            const int row = wv * 256 + g16 * 16 + c15;
            const float* wr = w + (size_t)row * CCH + q * 64;
            float part = 0.f;
#pragma unroll
            for (int j = 0; j < 16; ++j) {
                const float4 w4 = *(const float4*)(wr + j * 4);
                const float4 z4 = *(const float4*)&zsh[q * 64 + j * 4];
                part = fmaf(w4.x, z4.x, part);
                part = fmaf(w4.y, z4.y, part);
                part = fmaf(w4.z, z4.z, part);
                part = fmaf(w4.w, z4.w, part);
            }
            part += __shfl_xor(part, 16, 64);
            part += __shfl_xor(part, 32, 64);
            const float v = part + bias[row];
            if (v > best) { best = v; bi = row; }   // rows ascending: > keeps lowest
        }
#pragma unroll
        for (int d = 1; d < 16; d <<= 1) {
            const float ob = __shfl_xor(best, d, 64);
            const int   oi = __shfl_xor(bi, d, 64);
            if (ob > best || (ob == best && oi < bi)) { best = ob; bi = oi; }
        }
        if (l == 0) { m_v[wv] = best; m_i[wv] = bi; }
        __syncthreads();
        if (tid == 0) {
            float v = m_v[0]; int i = m_i[0];
#pragma unroll
            for (int t = 1; t < 4; ++t)
                if (m_v[t] > v || (m_v[t] == v && m_i[t] < i)) { v = m_v[t]; i = m_i[t]; }
            idx16[pix] = (unsigned short)i;
            out[ZQ_SIZE + 1 + pix] = (float)i;
        }
    }
}

// ---------- K5: gather epilogue (overwrites z_q; zTh/zTl dead) --------------
__global__ __launch_bounds__(256) void gather_k(
    const float* __restrict__ embed, const unsigned short* __restrict__ idx16,
    float* __restrict__ out)
{
    __shared__ __align__(16) float tile[64][257];
    __shared__ int indsh[64];

    const int tid = threadIdx.x;
    const int blk = blockIdx.x;
    const int b = blk >> 6, p0 = (blk & 63) << 6;
    const int pix0 = blk * 64;

    if (tid < 64) indsh[tid] = (int)idx16[pix0 + tid];
    __syncthreads();

    const int lq = tid & 63, wq = tid >> 6;
    for (int it = 0; it < 16; ++it) {
        const int p   = it * 4 + wq;
        const int row = indsh[p];
        const float4 e = *(const float4*)(embed + (size_t)row * DD + lq * 4);
        tile[p][lq * 4 + 0] = e.x;
        tile[p][lq * 4 + 1] = e.y;
        tile[p][lq * 4 + 2] = e.z;
        tile[p][lq * 4 + 3] = e.w;
    }
    __syncthreads();
    float* outz = out + (size_t)b * DD * HWP + p0;
    for (int dd = 0; dd < 64; ++dd) {
        const int d = dd * 4 + wq;
        outz[(size_t)d * HWP + lq] = tile[lq][d];
    }
}

extern "C" void kernel_launch(void* const* d_in, const int* in_sizes, int n_in,
                              void* d_out, int out_size, void* d_ws, size_t ws_size,
                              hipStream_t stream) {
    const float* z     = (const float*)d_in[0];
    const float* w     = (const float*)d_in[1];
    const float* bias  = (const float*)d_in[2];
    const float* embed = (const float*)d_in[3];
    float* out = (float*)d_out;

    // ws (1.14 MB — proven budget): wh 512K | wl 512K | idx16 64K | wcount | wlist
    _Float16* wh = (_Float16*)d_ws;
    _Float16* wl = (_Float16*)((char*)d_ws + 524288);
    unsigned short* idx16 = (unsigned short*)((char*)d_ws + 1048576);
    int* wcount = (int*)((char*)d_ws + 1114112);
    int* wlist  = (int*)((char*)d_ws + 1114368);

    // d_out scratch (dead before gather_k overwrites with z_q):
    //   zTh [0,16MB) | zTl [16,32MB)
    _Float16* zTh = (_Float16*)d_out;
    _Float16* zTl = (_Float16*)((char*)d_out + 16777216);

    hipLaunchKernelGGL(split_w_k,   dim3(1024), dim3(256), 0, stream, w, wh, wl, wcount);
    hipLaunchKernelGGL(split_zt_k,  dim3(2048), dim3(256), 0, stream, z, zTh, zTl);
    hipLaunchKernelGGL(mfma_full_k, dim3(1024), dim3(256), 0, stream,
                       zTh, zTl, wh, wl, bias, idx16, wcount, wlist, out);
    hipLaunchKernelGGL(fixup_k,     dim3(256),  dim3(256), 0, stream,
                       z, w, bias, wcount, wlist, idx16, out);
    hipLaunchKernelGGL(gather_k,    dim3(512),  dim3(256), 0, stream,
                       embed, idx16, out);
}

// Round 9
// 216.122 us; speedup vs baseline: 1.7218x; 1.2195x over previous
//
#include <hip/hip_runtime.h>
#include <math.h>

#define HWP 4096
#define CCH 256
#define NN  1024
#define DD  256
#define ZQ_SIZE (8 * DD * HWP)       // 8388608 floats = 33554432 B
#define MARGIN 1e-4f
#define WLCAP 4096

typedef _Float16 h8 __attribute__((ext_vector_type(8)));
typedef float    f4 __attribute__((ext_vector_type(4)));

// ---------- K1: split w -> SWIZZLED fragment order ----------
// whS/wlS layout: [r16 0..63][kc 0..7][lane 0..63][j 0..7] halfs.
// Fragment (r16,kc): lane l holds row r16*16+(l&15), k = kc*32+(l>>4)*8+j.
__global__ __launch_bounds__(256) void split_w_k(
    const float* __restrict__ w, _Float16* __restrict__ whS, _Float16* __restrict__ wlS,
    int* __restrict__ wcount)
{
    if (blockIdx.x == 0 && threadIdx.x == 0) *wcount = 0;
    const int t = blockIdx.x * 256 + threadIdx.x;   // 32768 = 512 frags x 64 lanes
    const int l = t & 63;
    const int frag = t >> 6;
    const int kc = frag & 7, r16 = frag >> 3;
    const int row = r16 * 16 + (l & 15);
    const int c   = kc * 32 + (l >> 4) * 8;
    const float* src = w + (size_t)row * CCH + c;
    _Float16 hv[8], lv[8];
#pragma unroll
    for (int j = 0; j < 8; ++j) {
        const float x = src[j];
        const _Float16 h = (_Float16)x;
        hv[j] = h;
        lv[j] = (_Float16)(x - (float)h);
    }
    *(h8*)(whS + (size_t)t * 8) = *(const h8*)hv;
    *(h8*)(wlS + (size_t)t * 8) = *(const h8*)lv;
}

// ---------- K2: z -> SWIZZLED zhS/zlS fragment order ----------
// zhS layout: [p16 0..2047][kc 0..7][lane][8]. Transpose via LDS (validated),
// store addressing changed to fragment order.
__global__ __launch_bounds__(256) void split_zt_k(
    const float* __restrict__ z, _Float16* __restrict__ zhS, _Float16* __restrict__ zlS)
{
    __shared__ float t[64][68];
    const int tid = threadIdx.x;
    const int pt  = blockIdx.x >> 2;                 // 512 pixel-tiles of 64
    const int ct  = blockIdx.x & 3;                  // 4 c-tiles of 64
    const int b   = pt >> 6;
    const int p0  = (pt & 63) << 6;
    const int c0  = ct << 6;
    const float* zb = z + ((size_t)b * CCH + c0) * HWP + p0;
    {
        const int px4 = tid & 15, cr = tid >> 4;
#pragma unroll
        for (int it = 0; it < 4; ++it) {
            const int c = it * 16 + cr;
            const float4 v = *(const float4*)(zb + (size_t)c * HWP + px4 * 4);
            *(float4*)&t[c][px4 * 4] = v;
        }
    }
    __syncthreads();
    {
        const int c8 = tid & 7, pxl = tid >> 3;      // 32 px per pass
#pragma unroll
        for (int it = 0; it < 2; ++it) {
            const int px = it * 32 + pxl;            // 0..63 in tile
            _Float16 hv[8], lv[8];
#pragma unroll
            for (int i = 0; i < 8; ++i) {
                const float x = t[c8 * 8 + i][px];
                const _Float16 h = (_Float16)x;
                hv[i] = h;
                lv[i] = (_Float16)(x - (float)h);
            }
            const int pxg  = pt * 64 + px;
            const int p16  = pxg >> 4;
            const int kc   = ct * 2 + (c8 >> 2);     // c = ct*64 + c8*8
            const int lane = (pxg & 15) + 16 * (c8 & 3);
            const size_t off = (((size_t)p16 * 8 + kc) * 64 + lane) * 8;
            *(h8*)(zhS + off) = *(const h8*)hv;
            *(h8*)(zlS + off) = *(const h8*)lv;
        }
    }
}

// ---------- K3: register-streamed MFMA GEMM + top2 + worklist ----------
// 512 blocks x 256 thr (4 waves). Block: 64 px x 1024 n. Wave tile 64px x 64n:
// nt-loop of 4, wave wv owns n in [nt*256 + wv*64, +64). All operand loads are
// lane-contiguous dwordx4 from L2 (pre-swizzled); NO LDS, NO barriers in the
// K-loop. 3 products zh*wh + zh*wl + zl*wh (validated numerics since R3).
__global__ __launch_bounds__(256, 2) void mfma_gemm_k(
    const _Float16* __restrict__ zhS, const _Float16* __restrict__ zlS,
    const _Float16* __restrict__ whS, const _Float16* __restrict__ wlS,
    const float* __restrict__ bias,
    unsigned short* __restrict__ idx16, int* __restrict__ wcount,
    int* __restrict__ wlist, float* __restrict__ out)
{
    __shared__ float s_best[4][64];
    __shared__ float s_sec [4][64];
    __shared__ int   s_idx [4][64];

    const int tid = threadIdx.x;
    const int l   = tid & 63;
    const int wv  = tid >> 6;
    const int c15 = l & 15, g = l >> 4;
    const int pix0  = blockIdx.x * 64;
    const int p16_0 = blockIdx.x * 4;

    float best[16], sec[16]; int bidx[16];
#pragma unroll
    for (int s = 0; s < 16; ++s) { best[s] = -INFINITY; sec[s] = -INFINITY; bidx[s] = 0; }

#pragma unroll 1
    for (int nt = 0; nt < 4; ++nt) {
        const int n0 = nt * 256 + wv * 64;
        const int r16_0 = n0 >> 4;
        f4 acc[4][4];
#pragma unroll
        for (int mf = 0; mf < 4; ++mf)
#pragma unroll
            for (int nf = 0; nf < 4; ++nf) acc[mf][nf] = (f4)0.f;

#pragma unroll 2
        for (int kc = 0; kc < 8; ++kc) {
            h8 ah[4], al[4], bh[4], bl[4];
#pragma unroll
            for (int mf = 0; mf < 4; ++mf) {
                const size_t ao = (((size_t)(p16_0 + mf) * 8 + kc) * 64 + l) * 8;
                ah[mf] = *(const h8*)(zhS + ao);
                al[mf] = *(const h8*)(zlS + ao);
            }
#pragma unroll
            for (int nf = 0; nf < 4; ++nf) {
                const size_t bo = (((size_t)(r16_0 + nf) * 8 + kc) * 64 + l) * 8;
                bh[nf] = *(const h8*)(whS + bo);
                bl[nf] = *(const h8*)(wlS + bo);
            }
#pragma unroll
            for (int mf = 0; mf < 4; ++mf)
#pragma unroll
                for (int nf = 0; nf < 4; ++nf) {
                    acc[mf][nf] = __builtin_amdgcn_mfma_f32_16x16x32_f16(ah[mf], bh[nf], acc[mf][nf], 0, 0, 0);
                    acc[mf][nf] = __builtin_amdgcn_mfma_f32_16x16x32_f16(ah[mf], bl[nf], acc[mf][nf], 0, 0, 0);
                    acc[mf][nf] = __builtin_amdgcn_mfma_f32_16x16x32_f16(al[mf], bh[nf], acc[mf][nf], 0, 0, 0);
                }
        }
        // fold (+bias) into per-lane top2 (each lane's n ascend -> strict >)
#pragma unroll
        for (int nf = 0; nf < 4; ++nf) {
            const int n_abs = n0 + nf * 16 + c15;
            const float bv = bias[n_abs];
#pragma unroll
            for (int mf = 0; mf < 4; ++mf)
#pragma unroll
                for (int r = 0; r < 4; ++r) {
                    const float v = acc[mf][nf][r] + bv;
                    const int s = mf * 4 + r;
                    if (v > best[s]) { sec[s] = best[s]; best[s] = v; bidx[s] = n_abs; }
                    else if (v > sec[s]) sec[s] = v;
                }
        }
    }

    // butterfly over the 16 col-lanes (validated)
#pragma unroll
    for (int d = 1; d < 16; d <<= 1) {
#pragma unroll
        for (int s = 0; s < 16; ++s) {
            const float ob = __shfl_xor(best[s], d, 64);
            const float os = __shfl_xor(sec[s], d, 64);
            const int   oi = __shfl_xor(bidx[s], d, 64);
            if (ob > best[s])       { sec[s] = fmaxf(best[s], os); best[s] = ob; bidx[s] = oi; }
            else if (ob == best[s]) { sec[s] = ob; bidx[s] = (oi < bidx[s]) ? oi : bidx[s]; }
            else                    { sec[s] = fmaxf(sec[s], ob); }
        }
    }
    // publish: slot s -> pixel (s>>2)*16 + g*4 + (s&3)
#pragma unroll
    for (int s = 0; s < 16; ++s) {
        if (c15 == s) {
            const int px = (s >> 2) * 16 + g * 4 + (s & 3);   // 0..63
            s_best[wv][px] = best[s];
            s_sec [wv][px] = sec[s];
            s_idx [wv][px] = bidx[s];
        }
    }
    __syncthreads();
    if (tid < 64) {
        float b0 = s_best[0][tid], s0 = s_sec[0][tid]; int i0 = s_idx[0][tid];
#pragma unroll
        for (int c = 1; c < 4; ++c) {
            const float ob = s_best[c][tid], os = s_sec[c][tid];
            const int   oi = s_idx[c][tid];
            // waves own interleaved n-ranges: explicit min-idx tie-break
            if (ob > b0 || (ob == b0 && oi < i0)) { s0 = fmaxf(b0, os); b0 = ob; i0 = oi; }
            else                                  { s0 = fmaxf(s0, ob); }
        }
        const int pix = pix0 + tid;
        idx16[pix] = (unsigned short)i0;
        out[ZQ_SIZE + 1 + pix] = (float)i0;
        if (b0 - s0 < MARGIN) {
            const int pos = atomicAdd(wcount, 1);
            if (pos < WLCAP) wlist[pos] = pix;
        }
    }
    if (blockIdx.x == 0 && tid == 0) out[ZQ_SIZE] = 0.0f;
}

// ---------- K4: exact-fp32 fixup (R8-validated) ----------
__global__ __launch_bounds__(256) void fixup_k(
    const float* __restrict__ z, const float* __restrict__ w,
    const float* __restrict__ bias,
    const int* __restrict__ wcount, const int* __restrict__ wlist,
    unsigned short* __restrict__ idx16, float* __restrict__ out)
{
    __shared__ float zsh[256];
    __shared__ float m_v[4];
    __shared__ int   m_i[4];

    const int tid = threadIdx.x;
    const int l = tid & 63, wv = tid >> 6;
    const int c15 = l & 15, q = l >> 4;
    int nw = *wcount;
    if (nw > WLCAP) nw = WLCAP;

    for (int e = blockIdx.x; e < nw; e += 256) {
        const int pix = wlist[e];
        const int b = pix >> 12, p = pix & 4095;
        __syncthreads();
        zsh[tid] = z[((size_t)b * CCH + tid) * HWP + p];
        __syncthreads();

        float best = -INFINITY; int bi = 0;
        for (int g16 = 0; g16 < 16; ++g16) {
            const int row = wv * 256 + g16 * 16 + c15;
            const float* wr = w + (size_t)row * CCH + q * 64;
            float part = 0.f;
#pragma unroll
            for (int j = 0; j < 16; ++j) {
                const float4 w4 = *(const float4*)(wr + j * 4);
                const float4 z4 = *(const float4*)&zsh[q * 64 + j * 4];
                part = fmaf(w4.x, z4.x, part);
                part = fmaf(w4.y, z4.y, part);
                part = fmaf(w4.z, z4.z, part);
                part = fmaf(w4.w, z4.w, part);
            }
            part += __shfl_xor(part, 16, 64);
            part += __shfl_xor(part, 32, 64);
            const float v = part + bias[row];
            if (v > best) { best = v; bi = row; }
        }
#pragma unroll
        for (int d = 1; d < 16; d <<= 1) {
            const float ob = __shfl_xor(best, d, 64);
            const int   oi = __shfl_xor(bi, d, 64);
            if (ob > best || (ob == best && oi < bi)) { best = ob; bi = oi; }
        }
        if (l == 0) { m_v[wv] = best; m_i[wv] = bi; }
        __syncthreads();
        if (tid == 0) {
            float v = m_v[0]; int i = m_i[0];
#pragma unroll
            for (int t = 1; t < 4; ++t)
                if (m_v[t] > v || (m_v[t] == v && m_i[t] < i)) { v = m_v[t]; i = m_i[t]; }
            idx16[pix] = (unsigned short)i;
            out[ZQ_SIZE + 1 + pix] = (float)i;
        }
    }
}

// ---------- K5: gather epilogue (overwrites z_q; zhS/zlS dead) --------------
__global__ __launch_bounds__(256) void gather_k(
    const float* __restrict__ embed, const unsigned short* __restrict__ idx16,
    float* __restrict__ out)
{
    __shared__ __align__(16) float tile[64][257];
    __shared__ int indsh[64];

    const int tid = threadIdx.x;
    const int blk = blockIdx.x;
    const int b = blk >> 6, p0 = (blk & 63) << 6;
    const int pix0 = blk * 64;

    if (tid < 64) indsh[tid] = (int)idx16[pix0 + tid];
    __syncthreads();

    const int lq = tid & 63, wq = tid >> 6;
    for (int it = 0; it < 16; ++it) {
        const int p   = it * 4 + wq;
        const int row = indsh[p];
        const float4 e = *(const float4*)(embed + (size_t)row * DD + lq * 4);
        tile[p][lq * 4 + 0] = e.x;
        tile[p][lq * 4 + 1] = e.y;
        tile[p][lq * 4 + 2] = e.z;
        tile[p][lq * 4 + 3] = e.w;
    }
    __syncthreads();
    float* outz = out + (size_t)b * DD * HWP + p0;
    for (int dd = 0; dd < 64; ++dd) {
        const int d = dd * 4 + wq;
        outz[(size_t)d * HWP + lq] = tile[lq][d];
    }
}

extern "C" void kernel_launch(void* const* d_in, const int* in_sizes, int n_in,
                              void* d_out, int out_size, void* d_ws, size_t ws_size,
                              hipStream_t stream) {
    const float* z     = (const float*)d_in[0];
    const float* w     = (const float*)d_in[1];
    const float* bias  = (const float*)d_in[2];
    const float* embed = (const float*)d_in[3];
    float* out = (float*)d_out;

    // ws (1.14 MB — proven budget): whS 512K | wlS 512K | idx16 64K | wcount | wlist
    _Float16* whS = (_Float16*)d_ws;
    _Float16* wlS = (_Float16*)((char*)d_ws + 524288);
    unsigned short* idx16 = (unsigned short*)((char*)d_ws + 1048576);
    int* wcount = (int*)((char*)d_ws + 1114112);
    int* wlist  = (int*)((char*)d_ws + 1114368);

    // d_out scratch (dead before gather_k overwrites with z_q):
    //   zhS [0,16MB) | zlS [16,32MB)
    _Float16* zhS = (_Float16*)d_out;
    _Float16* zlS = (_Float16*)((char*)d_out + 16777216);

    hipLaunchKernelGGL(split_w_k,   dim3(128),  dim3(256), 0, stream, w, whS, wlS, wcount);
    hipLaunchKernelGGL(split_zt_k,  dim3(2048), dim3(256), 0, stream, z, zhS, zlS);
    hipLaunchKernelGGL(mfma_gemm_k, dim3(512),  dim3(256), 0, stream,
                       zhS, zlS, whS, wlS, bias, idx16, wcount, wlist, out);
    hipLaunchKernelGGL(fixup_k,     dim3(256),  dim3(256), 0, stream,
                       z, w, bias, wcount, wlist, idx16, out);
    hipLaunchKernelGGL(gather_k,    dim3(512),  dim3(256), 0, stream,
                       embed, idx16, out);
}

// Round 11
// 185.963 us; speedup vs baseline: 2.0010x; 1.1622x over previous
//
#include <hip/hip_runtime.h>
#include <math.h>

#define HWP 4096
#define CCH 256
#define NN  1024
#define DD  256
#define ZQ_SIZE (8 * DD * HWP)       // 8388608 floats
#define MARGIN 1e-4f
#define WLCAP 4096

typedef _Float16 h8 __attribute__((ext_vector_type(8)));
typedef float    f4 __attribute__((ext_vector_type(4)));

// ---------- K1: split w -> SWIZZLED fragment order (R9-validated) ----------
// whS/wlS: [r16 0..63][kc 0..7][lane 0..63][j 0..7] halfs.
__global__ __launch_bounds__(256) void split_w_k(
    const float* __restrict__ w, _Float16* __restrict__ whS, _Float16* __restrict__ wlS,
    int* __restrict__ wcount)
{
    if (blockIdx.x == 0 && threadIdx.x == 0) *wcount = 0;
    const int t = blockIdx.x * 256 + threadIdx.x;
    const int l = t & 63;
    const int frag = t >> 6;
    const int kc = frag & 7, r16 = frag >> 3;
    const int row = r16 * 16 + (l & 15);
    const int c   = kc * 32 + (l >> 4) * 8;
    const float* src = w + (size_t)row * CCH + c;
    _Float16 hv[8], lv[8];
#pragma unroll
    for (int j = 0; j < 8; ++j) {
        const float x = src[j];
        const _Float16 h = (_Float16)x;
        hv[j] = h;
        lv[j] = (_Float16)(x - (float)h);
    }
    *(h8*)(whS + (size_t)t * 8) = *(const h8*)hv;
    *(h8*)(wlS + (size_t)t * 8) = *(const h8*)lv;
}

// ---------- K2: fused z-split + MFMA GEMM + top2 + gather epilogue ----------
// 512 blocks x 256 thr (4 waves). Block: 64 px x all 1024 n.
// LDS: zh [0,32K) | zl [32K,64K) | merge [64K,67K).  (R10's bug: these were
// sized 16K — 64px x 256c x 2B = 32K per array. Now correct.)
// K-loop: A via ds_read_b128 (lgkm), B via lane-contiguous dwordx4 from L2
// (vmcnt) — independent counters, no barriers. 3 products (validated R3-R9).
__global__ __launch_bounds__(256, 2) void mfma_gemm_k(
    const float* __restrict__ z,
    const _Float16* __restrict__ whS, const _Float16* __restrict__ wlS,
    const float* __restrict__ bias, const float* __restrict__ embed,
    int* __restrict__ wcount, int* __restrict__ wlist,
    float* __restrict__ out)
{
    __shared__ __align__(16) char smem[68608];
    __shared__ int indsh2[64];
    float* s_best = (float*)(smem + 65536);     // [4][64]
    float* s_sec  = (float*)(smem + 66560);
    int*   s_idx  = (int*)  (smem + 67584);

    const int tid = threadIdx.x;
    const int l   = tid & 63;
    const int wv  = tid >> 6;
    const int c15 = l & 15, g = l >> 4;
    const int pix0 = blockIdx.x * 64;
    const int b = pix0 >> 12, p0 = pix0 & 4095;

    // ---- Stage A: z -> hi/lo fp16 frag-order LDS ----
    // Frag (p16,kc) base = (p16*8+kc)*1024 B; lane entry +lane*16 B.
    {
        const int px = tid & 63;
        const int p16 = px >> 4;
        const float* zb = z + (size_t)b * CCH * HWP + p0 + px;
#pragma unroll
        for (int it = 0; it < 8; ++it) {
            const int cg = wv * 8 + it;          // c-group of 8 (0..31)
            const int c = cg * 8;
            float xv[8];
#pragma unroll
            for (int i = 0; i < 8; ++i) xv[i] = zb[(size_t)(c + i) * HWP];
            _Float16 hv[8], lv[8];
#pragma unroll
            for (int i = 0; i < 8; ++i) {
                const _Float16 h = (_Float16)xv[i];
                hv[i] = h;
                lv[i] = (_Float16)(xv[i] - (float)h);
            }
            const int kc = cg >> 2;
            const int lane = (px & 15) + 16 * (cg & 3);
            const int off = ((p16 * 8 + kc) * 64 + lane) * 16;   // bytes, < 32768
            *(h8*)(smem + off)         = *(const h8*)hv;
            *(h8*)(smem + 32768 + off) = *(const h8*)lv;
        }
    }
    __syncthreads();

    float best[16], sec[16]; int bidx[16];
#pragma unroll
    for (int s = 0; s < 16; ++s) { best[s] = -INFINITY; sec[s] = -INFINITY; bidx[s] = 0; }

#pragma unroll 1
    for (int nt = 0; nt < 4; ++nt) {
        const int n0 = nt * 256 + wv * 64;
        const int r16_0 = n0 >> 4;
        f4 acc[4][4];
#pragma unroll
        for (int mf = 0; mf < 4; ++mf)
#pragma unroll
            for (int nf = 0; nf < 4; ++nf) acc[mf][nf] = (f4)0.f;

#pragma unroll 2
        for (int kc = 0; kc < 8; ++kc) {
            h8 ah[4], al[4], bh[4], bl[4];
#pragma unroll
            for (int mf = 0; mf < 4; ++mf) {
                const int ao = ((mf * 8 + kc) * 64 + l) * 16;
                ah[mf] = *(const h8*)(smem + ao);
                al[mf] = *(const h8*)(smem + 32768 + ao);
            }
#pragma unroll
            for (int nf = 0; nf < 4; ++nf) {
                const size_t bo = (((size_t)(r16_0 + nf) * 8 + kc) * 64 + l) * 8;
                bh[nf] = *(const h8*)(whS + bo);
                bl[nf] = *(const h8*)(wlS + bo);
            }
#pragma unroll
            for (int mf = 0; mf < 4; ++mf)
#pragma unroll
                for (int nf = 0; nf < 4; ++nf) {
                    acc[mf][nf] = __builtin_amdgcn_mfma_f32_16x16x32_f16(ah[mf], bh[nf], acc[mf][nf], 0, 0, 0);
                    acc[mf][nf] = __builtin_amdgcn_mfma_f32_16x16x32_f16(ah[mf], bl[nf], acc[mf][nf], 0, 0, 0);
                    acc[mf][nf] = __builtin_amdgcn_mfma_f32_16x16x32_f16(al[mf], bh[nf], acc[mf][nf], 0, 0, 0);
                }
        }
        // fold (+bias) into per-lane top2 (each lane's n ascend -> strict >)
#pragma unroll
        for (int nf = 0; nf < 4; ++nf) {
            const int n_abs = n0 + nf * 16 + c15;
            const float bv = bias[n_abs];
#pragma unroll
            for (int mf = 0; mf < 4; ++mf)
#pragma unroll
                for (int r = 0; r < 4; ++r) {
                    const float v = acc[mf][nf][r] + bv;
                    const int s = mf * 4 + r;
                    if (v > best[s]) { sec[s] = best[s]; best[s] = v; bidx[s] = n_abs; }
                    else if (v > sec[s]) sec[s] = v;
                }
        }
    }

    // butterfly over the 16 col-lanes (validated)
#pragma unroll
    for (int d = 1; d < 16; d <<= 1) {
#pragma unroll
        for (int s = 0; s < 16; ++s) {
            const float ob = __shfl_xor(best[s], d, 64);
            const float os = __shfl_xor(sec[s], d, 64);
            const int   oi = __shfl_xor(bidx[s], d, 64);
            if (ob > best[s])       { sec[s] = fmaxf(best[s], os); best[s] = ob; bidx[s] = oi; }
            else if (ob == best[s]) { sec[s] = ob; bidx[s] = (oi < bidx[s]) ? oi : bidx[s]; }
            else                    { sec[s] = fmaxf(sec[s], ob); }
        }
    }
    // publish: slot s -> pixel (s>>2)*16 + g*4 + (s&3)
#pragma unroll
    for (int s = 0; s < 16; ++s) {
        if (c15 == s) {
            const int px = (s >> 2) * 16 + g * 4 + (s & 3);
            s_best[wv * 64 + px] = best[s];
            s_sec [wv * 64 + px] = sec[s];
            s_idx [wv * 64 + px] = bidx[s];
        }
    }
    __syncthreads();
    if (tid < 64) {
        float b0 = s_best[tid], s0 = s_sec[tid]; int i0 = s_idx[tid];
#pragma unroll
        for (int c = 1; c < 4; ++c) {
            const float ob = s_best[c * 64 + tid], os = s_sec[c * 64 + tid];
            const int   oi = s_idx[c * 64 + tid];
            if (ob > b0 || (ob == b0 && oi < i0)) { s0 = fmaxf(b0, os); b0 = ob; i0 = oi; }
            else                                  { s0 = fmaxf(s0, ob); }
        }
        const int pix = pix0 + tid;
        indsh2[tid] = i0;
        out[ZQ_SIZE + 1 + pix] = (float)i0;
        if (b0 - s0 < MARGIN) {
            const int pos = atomicAdd(wcount, 1);
            if (pos < WLCAP) wlist[pos] = pix;
        }
    }
    if (blockIdx.x == 0 && tid == 0) out[ZQ_SIZE] = 0.0f;
    __syncthreads();   // merge consumed; staging LDS dead -> reuse as tile

    // ---- Gather epilogue: 2 passes of 32 px through a [32][257] LDS tile ----
    float (*tile)[257] = (float (*)[257])smem;   // 32896 B, within dead 64 KB
    const int lq = tid & 63, wq = tid >> 6;
    const int l32 = tid & 31, dq = tid >> 5;
#pragma unroll 1
    for (int pp = 0; pp < 2; ++pp) {
#pragma unroll
        for (int it = 0; it < 8; ++it) {
            const int pl = it * 4 + wq;          // 0..31
            const int row = indsh2[pp * 32 + pl];
            const float4 e = *(const float4*)(embed + (size_t)row * DD + lq * 4);
            tile[pl][lq * 4 + 0] = e.x;
            tile[pl][lq * 4 + 1] = e.y;
            tile[pl][lq * 4 + 2] = e.z;
            tile[pl][lq * 4 + 3] = e.w;
        }
        __syncthreads();
        float* outz = out + (size_t)b * DD * HWP + p0 + pp * 32;
#pragma unroll
        for (int dd = 0; dd < 32; ++dd) {
            const int d = dd * 8 + dq;
            outz[(size_t)d * HWP + l32] = tile[l32][d];
        }
        __syncthreads();
    }
}

// ---------- K3: exact-fp32 fixup (R8-validated core) + z_q rewrite ----------
__global__ __launch_bounds__(256) void fixup_k(
    const float* __restrict__ z, const float* __restrict__ w,
    const float* __restrict__ bias, const float* __restrict__ embed,
    const int* __restrict__ wcount, const int* __restrict__ wlist,
    float* __restrict__ out)
{
    __shared__ float zsh[256];
    __shared__ float m_v[4];
    __shared__ int   m_i[4];
    __shared__ int   s_i;

    const int tid = threadIdx.x;
    const int l = tid & 63, wv = tid >> 6;
    const int c15 = l & 15, q = l >> 4;
    int nw = *wcount;
    if (nw > WLCAP) nw = WLCAP;

    for (int e = blockIdx.x; e < nw; e += 256) {
        const int pix = wlist[e];
        const int b = pix >> 12, p = pix & 4095;
        __syncthreads();
        zsh[tid] = z[((size_t)b * CCH + tid) * HWP + p];
        __syncthreads();

        float best = -INFINITY; int bi = 0;
        for (int g16 = 0; g16 < 16; ++g16) {
            const int row = wv * 256 + g16 * 16 + c15;
            const float* wr = w + (size_t)row * CCH + q * 64;
            float part = 0.f;
#pragma unroll
            for (int j = 0; j < 16; ++j) {
                const float4 w4 = *(const float4*)(wr + j * 4);
                const float4 z4 = *(const float4*)&zsh[q * 64 + j * 4];
                part = fmaf(w4.x, z4.x, part);
                part = fmaf(w4.y, z4.y, part);
                part = fmaf(w4.z, z4.z, part);
                part = fmaf(w4.w, z4.w, part);
            }
            part += __shfl_xor(part, 16, 64);
            part += __shfl_xor(part, 32, 64);
            const float v = part + bias[row];
            if (v > best) { best = v; bi = row; }
        }
#pragma unroll
        for (int d = 1; d < 16; d <<= 1) {
            const float ob = __shfl_xor(best, d, 64);
            const int   oi = __shfl_xor(bi, d, 64);
            if (ob > best || (ob == best && oi < bi)) { best = ob; bi = oi; }
        }
        if (l == 0) { m_v[wv] = best; m_i[wv] = bi; }
        __syncthreads();
        if (tid == 0) {
            float v = m_v[0]; int i = m_i[0];
#pragma unroll
            for (int t = 1; t < 4; ++t)
                if (m_v[t] > v || (m_v[t] == v && m_i[t] < i)) { v = m_v[t]; i = m_i[t]; }
            s_i = i;
            out[ZQ_SIZE + 1 + pix] = (float)i;
        }
        __syncthreads();
        const int ii = s_i;
        out[((size_t)b * DD + tid) * HWP + p] = embed[(size_t)ii * DD + tid];
    }
}

extern "C" void kernel_launch(void* const* d_in, const int* in_sizes, int n_in,
                              void* d_out, int out_size, void* d_ws, size_t ws_size,
                              hipStream_t stream) {
    const float* z     = (const float*)d_in[0];
    const float* w     = (const float*)d_in[1];
    const float* bias  = (const float*)d_in[2];
    const float* embed = (const float*)d_in[3];
    float* out = (float*)d_out;

    // ws (1.02 MB — proven budget): whS 512K | wlS 512K | wcount | wlist
    _Float16* whS = (_Float16*)d_ws;
    _Float16* wlS = (_Float16*)((char*)d_ws + 524288);
    int* wcount = (int*)((char*)d_ws + 1048576);
    int* wlist  = (int*)((char*)d_ws + 1048832);

    hipLaunchKernelGGL(split_w_k,   dim3(128), dim3(256), 0, stream, w, whS, wlS, wcount);
    hipLaunchKernelGGL(mfma_gemm_k, dim3(512), dim3(256), 0, stream,
                       z, whS, wlS, bias, embed, wcount, wlist, out);
    hipLaunchKernelGGL(fixup_k,     dim3(256), dim3(256), 0, stream,
                       z, w, bias, embed, wcount, wlist, out);
}